// Round 14
// baseline (69.614 us; speedup 1.0000x reference)
//
#include <hip/hip_runtime.h>

// CustomMultiheadAttention on MI355X (gfx950).
// B=4 T=1024 S=1024 H=16 D=64 E=1024. Output fp32 [B,T,E].
//
// r14: r11 base (65.1us best; V back to LDS-staged -- V-direct dead per
// r12/r13) + P-pipeline: PV(i-1) overlaps QK(i) via double-buffered plds and
// V(i-1) held in registers. Accumulation order unchanged -> bitwise output.
//   proj_qkv : r11 verbatim.
//   attn_fwd : r11 + plds dbuf + deferred PV (T15-style dep-break).
//   out_proj : r10/r11 verbatim (~8us measured).
//
// Workspace (22 MB):
//   [0,8MB) qs bf16 [B*H,T,D] | [8,10) kb [H,S,D] | [10,12) vt [H,D,S]
//   [12,20) ctx bf16 [B*T,E]  | [20,22) wb [E,E]

typedef __attribute__((ext_vector_type(8))) short short8v;
typedef __attribute__((ext_vector_type(4))) short short4v;
typedef __attribute__((ext_vector_type(4))) float float4v;

#define MFMA_BF16(A, B, C) __builtin_amdgcn_mfma_f32_16x16x32_bf16(A, B, C, 0, 0, 0)

#if __has_builtin(__builtin_amdgcn_exp2f)
#define EXP2F(x) __builtin_amdgcn_exp2f(x)
#else
#define EXP2F(x) exp2f(x)
#endif

#define QSCALE 0.045084220027780106f   // log2(e)/32

__device__ __forceinline__ short f2bf(float f) {
  union { float f; unsigned u; } v; v.f = f;
  unsigned r = v.u + 0x7FFFu + ((v.u >> 16) & 1u);
  return (short)(r >> 16);
}

// pack 2 f32 -> 2 bf16 (RNE); S0 -> low half (validated r11)
__device__ __forceinline__ unsigned cvt_pk_bf16(float lo, float hi) {
  unsigned r;
  asm("v_cvt_pk_bf16_f32 %0, %1, %2" : "=v"(r) : "v"(lo), "v"(hi));
  return r;
}

// ---------------------------------------------------------------------------
// Kernel 1: per-head Q/K/V projections via MFMA + Wout fp32->bf16 cvt
// (tasks 6144..6655). Identical to r7/r8/r11 (passed).
// ---------------------------------------------------------------------------
__global__ __launch_bounds__(256) void proj_qkv(
    const float* __restrict__ query, const float* __restrict__ para,
    const float* __restrict__ Wq, const float* __restrict__ bq,
    const float* __restrict__ Wk, const float* __restrict__ bk,
    const float* __restrict__ Wv, const float* __restrict__ bv,
    const float* __restrict__ Wout,
    short* __restrict__ qs, short* __restrict__ kb, short* __restrict__ vt,
    short* __restrict__ wb) {
  const int task = blockIdx.x * 4 + (threadIdx.x >> 6);
  const int lane = threadIdx.x & 63;
  const int g = lane >> 4, c = lane & 15;

  if (task >= 6144) {   // ---- cvt Wout -> wb (512 wave-tasks, 2048 elems each)
    const int j = task - 6144;
    const float* src = Wout + j * 2048;
    short* dst = wb + j * 2048;
#pragma unroll
    for (int it = 0; it < 4; ++it) {
      const int off = it * 512 + lane * 8;
      float4v x0 = *(const float4v*)(src + off);
      float4v x1 = *(const float4v*)(src + off + 4);
      short8v v = (short8v){ f2bf(x0.x), f2bf(x0.y), f2bf(x0.z), f2bf(x0.w),
                             f2bf(x1.x), f2bf(x1.y), f2bf(x1.z), f2bf(x1.w) };
      *(short8v*)(dst + off) = v;
    }
    return;
  }

  const float* W;
  const float* bias;
  const float* xrow;
  int type, h, tile, bh = 0;
  if (task < 4096) {
    type = 0; bh = task >> 6; tile = task & 63; h = bh & 15;
    xrow = query + ((bh >> 4) * 1024 + tile * 16 + c) * 1024 + h * 64;
    W = Wq; bias = bq;
  } else if (task < 5120) {
    int idx = task - 4096;
    type = 1; h = idx >> 6; tile = idx & 63;
    xrow = para + (tile * 16 + c) * 1024 + h * 64;
    W = Wk; bias = bk;
  } else {
    int idx = task - 5120;
    type = 2; h = idx >> 6; tile = idx & 63;
    xrow = para + (tile * 16 + c) * 1024 + h * 64;
    W = Wv; bias = bv;
  }

  short8v af[2];
#pragma unroll
  for (int kh = 0; kh < 2; ++kh) {
    const float* xp = xrow + kh * 32 + g * 8;
    float4v x0 = *(const float4v*)xp;
    float4v x1 = *(const float4v*)(xp + 4);
    af[kh] = (short8v){ f2bf(x0.x), f2bf(x0.y), f2bf(x0.z), f2bf(x0.w),
                        f2bf(x1.x), f2bf(x1.y), f2bf(x1.z), f2bf(x1.w) };
  }

#pragma unroll
  for (int dn = 0; dn < 4; ++dn) {
    float4v acc = (float4v){0.f, 0.f, 0.f, 0.f};
#pragma unroll
    for (int kh = 0; kh < 2; ++kh) {
      const float* wp = W + (dn * 16 + c) * 64 + kh * 32 + g * 8;
      float4v w0 = *(const float4v*)wp;
      float4v w1 = *(const float4v*)(wp + 4);
      short8v bfr = (short8v){ f2bf(w0.x), f2bf(w0.y), f2bf(w0.z), f2bf(w0.w),
                               f2bf(w1.x), f2bf(w1.y), f2bf(w1.z), f2bf(w1.w) };
      acc = MFMA_BF16(af[kh], bfr, acc);
    }
    const float bc = bias[dn * 16 + c];
    if (type == 0) {
#pragma unroll
      for (int r = 0; r < 4; ++r) {
        const int t = tile * 16 + 4 * g + r;
        qs[(bh * 1024 + t) * 64 + dn * 16 + c] = f2bf((acc[r] + bc) * QSCALE);
      }
    } else if (type == 1) {
#pragma unroll
      for (int r = 0; r < 4; ++r) {
        const int s = tile * 16 + 4 * g + r;
        kb[(h * 1024 + s) * 64 + dn * 16 + c] = f2bf(acc[r] + bc);
      }
    } else {
      short4v pk = (short4v){ f2bf(acc[0] + bc), f2bf(acc[1] + bc),
                              f2bf(acc[2] + bc), f2bf(acc[3] + bc) };
      *(short4v*)(vt + (h * 64 + dn * 16 + c) * 1024 + tile * 16 + 4 * g) = pk;
    }
  }
}

// ---------------------------------------------------------------------------
// Kernel 2: attention. r11 structure (512 blocks x 4 waves, 32 t-rows/wave,
// K+V LDS-staged dbuf) with PV deferred one iteration:
//   iter i: QK(i)->exp->pack->plds[i&1];  PV(i-1) from plds[(i-1)&1] x vfo.
// plds double-buffered (per-wave); V(i) loaded into vfo AFTER PV(i-1).
// Accumulation order into cacc/dacc unchanged -> output bitwise = r11.
// ---------------------------------------------------------------------------
__global__ __launch_bounds__(256, 2) void attn_fwd(
    const short* __restrict__ qs, const short* __restrict__ kb,
    const short* __restrict__ vt, short* __restrict__ ctx) {
  __shared__ __align__(16) short kv[2][4096];            // per buf: K 4KB|V 4KB
  __shared__ __align__(16) short plds[2][4][2][16][40];  // dbuf per-wave P
  const int tid = threadIdx.x;
  const int w = tid >> 6;
  const int lane = tid & 63;
  const int g = lane >> 4, c = lane & 15;
  const int bh = blockIdx.x & 63;          // XCD-swizzle: bh%8 == XCD
  const int b = bh >> 4, h = bh & 15;
  const int t0 = (blockIdx.x >> 6) * 128 + w * 32;

  // staging: per-thread pre-swizzled global src, linear LDS dest (r8/r11)
  const int kr = tid >> 3, kq = (tid & 7) ^ (kr & 7);
  const char* ksrc = (const char*)(kb + h * 65536) + kr * 128 + kq * 16;
  const int vd = tid >> 2, vq = (tid & 3) ^ ((vd >> 1) & 3);
  const char* vsrc = (const char*)(vt + h * 65536) + vd * 2048 + vq * 16;
  char* kdst = (char*)&kv[0][0] + tid * 16;
  char* vdst = (char*)&kv[0][0] + 4096 + tid * 16;

  int koff[2][2];
#pragma unroll
  for (int sm = 0; sm < 2; ++sm)
#pragma unroll
    for (int kh = 0; kh < 2; ++kh)
      koff[sm][kh] = (sm * 16 + c) * 128 + (((kh * 4 + g) ^ (c & 7)) * 16);
  int voff[4];
#pragma unroll
  for (int nt = 0; nt < 4; ++nt)
    voff[nt] = 4096 + (nt * 16 + c) * 64 + ((g ^ ((c >> 1) & 3)) * 16);

  const short* qbase = qs + (bh * 1024 + t0) * 64;
  short8v qf[2][2];
#pragma unroll
  for (int tn = 0; tn < 2; ++tn)
#pragma unroll
    for (int kh = 0; kh < 2; ++kh)
      qf[tn][kh] = *(const short8v*)(qbase + (tn * 16 + c) * 64 + kh * 32 + g * 8);

  float4v cacc[2][4];
#pragma unroll
  for (int tn = 0; tn < 2; ++tn)
#pragma unroll
    for (int nt = 0; nt < 4; ++nt)
      cacc[tn][nt] = (float4v){0.f, 0.f, 0.f, 0.f};
  float4v dacc[2];
  dacc[0] = (float4v){0.f, 0.f, 0.f, 0.f};
  dacc[1] = (float4v){0.f, 0.f, 0.f, 0.f};
  const short obf = (short)0x3F80;   // bf16 1.0
  const short8v ones = (short8v){obf, obf, obf, obf, obf, obf, obf, obf};

  short8v sk = *(const short8v*)ksrc;
  short8v sv = *(const short8v*)vsrc;
  *(short8v*)kdst = sk;
  *(short8v*)vdst = sv;

  short8v vfo[4];   // V(i-1) held in registers for the deferred PV

  const char* kv0 = (const char*)&kv[0][0];
#pragma unroll 1
  for (int i = 0; i <= 32; ++i) {
    if (i < 32) __syncthreads();          // K/V buf(i&1) ready (uniform cond)
    if (i < 31) {                         // issue next-tile global loads early
      sk = *(const short8v*)(ksrc + (i + 1) * 4096);
      sv = *(const short8v*)(vsrc + (i + 1) * 64);
    }

    const char* kvb = kv0 + (i & 1) * 8192;

    // early-issue P(i-1) fragment reads (prev plds buffer; own-wave data)
    short8v pa[2];
    if (i > 0) {
#pragma unroll
      for (int tn = 0; tn < 2; ++tn)
        pa[tn] = *(const short8v*)&plds[(i - 1) & 1][w][tn][c][g * 8];
    }

    if (i < 32) {
      short8v kf[2][2];
#pragma unroll
      for (int sm = 0; sm < 2; ++sm)
#pragma unroll
        for (int kh = 0; kh < 2; ++kh)
          kf[sm][kh] = *(const short8v*)(kvb + koff[sm][kh]);

      // QK^T(i) -> exp2 -> cvt_pk pack into plds[i&1]
#pragma unroll
      for (int sm = 0; sm < 2; ++sm)
#pragma unroll
        for (int tn = 0; tn < 2; ++tn) {
          float4v z = (float4v){0.f, 0.f, 0.f, 0.f};
          z = MFMA_BF16(kf[sm][0], qf[tn][0], z);
          z = MFMA_BF16(kf[sm][1], qf[tn][1], z);
          const float p0 = EXP2F(z[0]);
          const float p1 = EXP2F(z[1]);
          const float p2 = EXP2F(z[2]);
          const float p3 = EXP2F(z[3]);
          uint2 u;
          u.x = cvt_pk_bf16(p0, p1);   // s = 4g, 4g+1
          u.y = cvt_pk_bf16(p2, p3);   // s = 4g+2, 4g+3
          *(uint2*)&plds[i & 1][w][tn][c][sm * 16 + 4 * g] = u;
        }
    }

    // deferred PV(i-1): P(i-1) x V(i-1), accumulation order same as r11
    if (i > 0) {
#pragma unroll
      for (int tn = 0; tn < 2; ++tn) {
#pragma unroll
        for (int nt = 0; nt < 4; ++nt)
          cacc[tn][nt] = MFMA_BF16(pa[tn], vfo[nt], cacc[tn][nt]);
        dacc[tn] = MFMA_BF16(pa[tn], ones, dacc[tn]);
      }
    }

    // V(i) -> registers for next iteration's PV (after old vfo consumed)
    if (i < 32) {
#pragma unroll
      for (int nt = 0; nt < 4; ++nt)
        vfo[nt] = *(const short8v*)(kvb + voff[nt]);
    }

    asm volatile("" ::: "memory");

    if (i < 31) {   // write tile i+1 into the other K/V buffer
      *(short8v*)(kdst + ((i + 1) & 1) * 8192) = sk;
      *(short8v*)(vdst + ((i + 1) & 1) * 8192) = sv;
    }
  }

  const int orow0 = b * 1024 + t0;
#pragma unroll
  for (int tn = 0; tn < 2; ++tn) {
    float inv[4];
#pragma unroll
    for (int r = 0; r < 4; ++r) inv[r] = 1.0f / dacc[tn][r];
#pragma unroll
    for (int nt = 0; nt < 4; ++nt)
#pragma unroll
      for (int r = 0; r < 4; ++r) {
        const int row = orow0 + tn * 16 + 4 * g + r;
        ctx[row * 1024 + h * 64 + nt * 16 + c] = f2bf(cacc[tn][nt][r] * inv[r]);
      }
  }
}

// ---------------------------------------------------------------------------
// Kernel 3: out = ctx(bf16) @ Wout^T + bout. r10/r11-exact (~8us measured):
// 512 blocks (32m x 16n, 128x64 tile) x 4 waves as 2m x 2n (64x32/wave).
// A+B LDS-staged dbuf; LDS content [r][ch] = X[r][ch ^ ((r>>1)&3)].
// ---------------------------------------------------------------------------
__global__ __launch_bounds__(256, 2) void out_proj(
    const short* __restrict__ ctx, const short* __restrict__ wb,
    const float* __restrict__ bout, float* __restrict__ out) {
  __shared__ __align__(16) short ab[2][6144];   // per buf: A 8KB | B 4KB
  const int tid = threadIdx.x;
  const int w = tid >> 6;
  const int lane = tid & 63;
  const int g = lane >> 4, c = lane & 15;
  const int wm = w >> 1, wn = w & 1;
  const int mblk = (blockIdx.x & 31) * 128;
  const int n0 = (blockIdx.x >> 5) * 64;

  // staging (256 threads): A rows srow & srow+64 (same chunk XOR), B rows srow.
  const int srow = tid >> 2;                   // 0..63
  const int sq = (tid & 3) ^ ((srow >> 1) & 3);
  const char* asrc0 = (const char*)ctx + (mblk + srow) * 2048 + sq * 16;
  const char* asrc1 = asrc0 + 64 * 2048;
  const char* bsrc  = (const char*)wb + (n0 + srow) * 2048 + sq * 16;
  char* adst0 = (char*)&ab[0][0] + tid * 16;
  char* adst1 = (char*)&ab[0][0] + 4096 + tid * 16;
  char* bdst  = (char*)&ab[0][0] + 8192 + tid * 16;

  const int sw = (g ^ ((c >> 1) & 3)) * 16;
  int aoff[4], boff[2];
#pragma unroll
  for (int mt = 0; mt < 4; ++mt)
    aoff[mt] = (wm * 64 + mt * 16 + c) * 64 + sw;
#pragma unroll
  for (int nt = 0; nt < 2; ++nt)
    boff[nt] = 8192 + (wn * 32 + nt * 16 + c) * 64 + sw;

  float4v acc[4][2];
#pragma unroll
  for (int mt = 0; mt < 4; ++mt)
#pragma unroll
    for (int nt = 0; nt < 2; ++nt)
      acc[mt][nt] = (float4v){0.f, 0.f, 0.f, 0.f};

  // prologue: k-tile 0 -> buf 0
  short8v sa0 = *(const short8v*)asrc0;
  short8v sa1 = *(const short8v*)asrc1;
  short8v sbv = *(const short8v*)bsrc;
  *(short8v*)adst0 = sa0;
  *(short8v*)adst1 = sa1;
  *(short8v*)bdst = sbv;

  const char* ab0 = (const char*)&ab[0][0];
  for (int i = 0; i < 32; ++i) {
    __syncthreads();
    if (i < 31) {
      sa0 = *(const short8v*)(asrc0 + (i + 1) * 64);
      sa1 = *(const short8v*)(asrc1 + (i + 1) * 64);
      sbv = *(const short8v*)(bsrc + (i + 1) * 64);
    }
    const char* abb = ab0 + (i & 1) * 12288;
    short8v a[4], bb[2];
#pragma unroll
    for (int mt = 0; mt < 4; ++mt)
      a[mt] = *(const short8v*)(abb + aoff[mt]);
#pragma unroll
    for (int nt = 0; nt < 2; ++nt)
      bb[nt] = *(const short8v*)(abb + boff[nt]);
#pragma unroll
    for (int mt = 0; mt < 4; ++mt)
#pragma unroll
      for (int nt = 0; nt < 2; ++nt)
        acc[mt][nt] = MFMA_BF16(a[mt], bb[nt], acc[mt][nt]);
    if (i < 31) {
      *(short8v*)(adst0 + ((i + 1) & 1) * 12288) = sa0;
      *(short8v*)(adst1 + ((i + 1) & 1) * 12288) = sa1;
      *(short8v*)(bdst + ((i + 1) & 1) * 12288) = sbv;
    }
  }

  float bs[2];
#pragma unroll
  for (int nt = 0; nt < 2; ++nt) bs[nt] = bout[n0 + wn * 32 + nt * 16 + c];

  const int m0 = mblk + wm * 64;
#pragma unroll
  for (int mt = 0; mt < 4; ++mt)
#pragma unroll
    for (int nt = 0; nt < 2; ++nt)
#pragma unroll
      for (int r = 0; r < 4; ++r)
        out[(m0 + mt * 16 + 4 * g + r) * 1024 + n0 + wn * 32 + nt * 16 + c] =
            acc[mt][nt][r] + bs[nt];
}

// ---------------------------------------------------------------------------
extern "C" void kernel_launch(void* const* d_in, const int* in_sizes, int n_in,
                              void* d_out, int out_size, void* d_ws, size_t ws_size,
                              hipStream_t stream) {
  const float* query = (const float*)d_in[0];
  const float* para  = (const float*)d_in[1];
  const float* Wq = (const float*)d_in[2];
  const float* bq = (const float*)d_in[3];
  const float* Wk = (const float*)d_in[4];
  const float* bk = (const float*)d_in[5];
  const float* Wv = (const float*)d_in[6];
  const float* bv = (const float*)d_in[7];
  const float* Wout = (const float*)d_in[8];
  const float* bout = (const float*)d_in[9];
  float* out = (float*)d_out;

  char* ws = (char*)d_ws;
  short* qs  = (short*)(ws);                      // 8 MB
  short* kb  = (short*)(ws + (8u  << 20));        // 2 MB
  short* vt  = (short*)(ws + (10u << 20));        // 2 MB
  short* ctx = (short*)(ws + (12u << 20));        // 8 MB
  short* wb  = (short*)(ws + (20u << 20));        // 2 MB

  proj_qkv<<<dim3(1664), dim3(256), 0, stream>>>(query, para, Wq, bq, Wk, bk,
                                                 Wv, bv, Wout, qs, kb, vt, wb);
  attn_fwd<<<dim3(512), dim3(256), 0, stream>>>(qs, kb, vt, ctx);
  out_proj<<<dim3(512), dim3(256), 0, stream>>>(ctx, wb, bout, out);
}

// Round 15
// 63.706 us; speedup vs baseline: 1.0927x; 1.0927x over previous
//
#include <hip/hip_runtime.h>

// CustomMultiheadAttention on MI355X (gfx950).
// B=4 T=1024 S=1024 H=16 D=64 E=1024. Output fp32 [B,T,E].
//
// r15: r11 base (65.1us best) + Q-projection fused into attn's prologue
// (bit-identical math: proj's verbatim type-0 MFMA + f2bf((acc+bc)*QSCALE),
// staged via the kv LDS buffer before K/V staging begins). proj_qkv drops
// its 4096 Q-tasks (6656->2560) and the 16MB qs round-trip disappears.
//   proj_qkv : K/V proj + Wout cvt only (640 blocks).
//   attn_fwd : r11 + Q-proj prologue; K/V/P paths byte-identical to r11.
//   out_proj : r10/r11 verbatim (~8us measured).
// (r12/r13 V-direct and r14 P-pipeline all regressed -> reverted.)
//
// Workspace (22 MB):
//   [8,10) kb bf16 [H,S,D] | [10,12) vt [H,D,S]
//   [12,20) ctx bf16 [B*T,E] | [20,22) wb [E,E]   ([0,8) unused now)

typedef __attribute__((ext_vector_type(8))) short short8v;
typedef __attribute__((ext_vector_type(4))) short short4v;
typedef __attribute__((ext_vector_type(4))) float float4v;

#define MFMA_BF16(A, B, C) __builtin_amdgcn_mfma_f32_16x16x32_bf16(A, B, C, 0, 0, 0)

#if __has_builtin(__builtin_amdgcn_exp2f)
#define EXP2F(x) __builtin_amdgcn_exp2f(x)
#else
#define EXP2F(x) exp2f(x)
#endif

#define QSCALE 0.045084220027780106f   // log2(e)/32

__device__ __forceinline__ short f2bf(float f) {
  union { float f; unsigned u; } v; v.f = f;
  unsigned r = v.u + 0x7FFFu + ((v.u >> 16) & 1u);
  return (short)(r >> 16);
}

// pack 2 f32 -> 2 bf16 (RNE); S0 -> low half (validated r11)
__device__ __forceinline__ unsigned cvt_pk_bf16(float lo, float hi) {
  unsigned r;
  asm("v_cvt_pk_bf16_f32 %0, %1, %2" : "=v"(r) : "v"(lo), "v"(hi));
  return r;
}

// ---------------------------------------------------------------------------
// Kernel 1: K/V projections + Wout cvt. 640 blocks x 4 wave-tasks:
//   [0,1024) K | [1024,2048) V | [2048,2560) cvt. Bodies identical to r11.
// ---------------------------------------------------------------------------
__global__ __launch_bounds__(256) void proj_qkv(
    const float* __restrict__ para,
    const float* __restrict__ Wk, const float* __restrict__ bk,
    const float* __restrict__ Wv, const float* __restrict__ bv,
    const float* __restrict__ Wout,
    short* __restrict__ kb, short* __restrict__ vt, short* __restrict__ wb) {
  const int task = blockIdx.x * 4 + (threadIdx.x >> 6);
  const int lane = threadIdx.x & 63;
  const int g = lane >> 4, c = lane & 15;

  if (task >= 2048) {   // ---- cvt Wout -> wb (512 wave-tasks, 2048 elems each)
    const int j = task - 2048;
    const float* src = Wout + j * 2048;
    short* dst = wb + j * 2048;
#pragma unroll
    for (int it = 0; it < 4; ++it) {
      const int off = it * 512 + lane * 8;
      float4v x0 = *(const float4v*)(src + off);
      float4v x1 = *(const float4v*)(src + off + 4);
      short8v v = (short8v){ f2bf(x0.x), f2bf(x0.y), f2bf(x0.z), f2bf(x0.w),
                             f2bf(x1.x), f2bf(x1.y), f2bf(x1.z), f2bf(x1.w) };
      *(short8v*)(dst + off) = v;
    }
    return;
  }

  const int type = (task < 1024) ? 1 : 2;   // 1=K, 2=V (r11 type ids)
  const int idx = (task < 1024) ? task : task - 1024;
  const int h = idx >> 6, tile = idx & 63;
  const float* xrow = para + (tile * 16 + c) * 1024 + h * 64;
  const float* W = (type == 1) ? Wk : Wv;
  const float* bias = (type == 1) ? bk : bv;

  short8v af[2];
#pragma unroll
  for (int kh = 0; kh < 2; ++kh) {
    const float* xp = xrow + kh * 32 + g * 8;
    float4v x0 = *(const float4v*)xp;
    float4v x1 = *(const float4v*)(xp + 4);
    af[kh] = (short8v){ f2bf(x0.x), f2bf(x0.y), f2bf(x0.z), f2bf(x0.w),
                        f2bf(x1.x), f2bf(x1.y), f2bf(x1.z), f2bf(x1.w) };
  }

#pragma unroll
  for (int dn = 0; dn < 4; ++dn) {
    float4v acc = (float4v){0.f, 0.f, 0.f, 0.f};
#pragma unroll
    for (int kh = 0; kh < 2; ++kh) {
      const float* wp = W + (dn * 16 + c) * 64 + kh * 32 + g * 8;
      float4v w0 = *(const float4v*)wp;
      float4v w1 = *(const float4v*)(wp + 4);
      short8v bfr = (short8v){ f2bf(w0.x), f2bf(w0.y), f2bf(w0.z), f2bf(w0.w),
                               f2bf(w1.x), f2bf(w1.y), f2bf(w1.z), f2bf(w1.w) };
      acc = MFMA_BF16(af[kh], bfr, acc);
    }
    const float bc = bias[dn * 16 + c];
    if (type == 1) {
#pragma unroll
      for (int r = 0; r < 4; ++r) {
        const int s = tile * 16 + 4 * g + r;
        kb[(h * 1024 + s) * 64 + dn * 16 + c] = f2bf(acc[r] + bc);
      }
    } else {
      short4v pk = (short4v){ f2bf(acc[0] + bc), f2bf(acc[1] + bc),
                              f2bf(acc[2] + bc), f2bf(acc[3] + bc) };
      *(short4v*)(vt + (h * 64 + dn * 16 + c) * 1024 + tile * 16 + 4 * g) = pk;
    }
  }
}

// ---------------------------------------------------------------------------
// Kernel 2: attention. r11 structure (512 blocks x 4 waves, 32 t-rows/wave,
// K+V LDS-staged dbuf, cvt_pk pack, ones-MFMA denominator) + fused Q-proj:
// each wave computes its own Q rows (proj's verbatim type-0 math -> bit-
// identical), round-trips them through its 4KB slice of the kv buffer for
// the fragment-layout transpose, then the kv buffer is reclaimed for K/V.
// ---------------------------------------------------------------------------
__global__ __launch_bounds__(256, 4) void attn_fwd(
    const float* __restrict__ query,
    const float* __restrict__ Wq, const float* __restrict__ bq,
    const short* __restrict__ kb, const short* __restrict__ vt,
    short* __restrict__ ctx) {
  __shared__ __align__(16) short kv[2][4096];         // per buf: K 4KB | V 4KB
  __shared__ __align__(16) short plds[4][2][16][40];  // per-wave P tiles
  const int tid = threadIdx.x;
  const int w = tid >> 6;
  const int lane = tid & 63;
  const int g = lane >> 4, c = lane & 15;
  const int bh = blockIdx.x & 63;          // XCD-swizzle: bh%8 == XCD
  const int b = bh >> 4, h = bh & 15;
  const int t0 = (blockIdx.x >> 6) * 128 + w * 32;

  // ---- fused Q projection (bit-identical to r11's proj type-0 + qs read) --
  // per-wave [32][64] bf16 tile in the kv buffer (w*2048 shorts, exact fit)
  short* qreg = (short*)&kv[0][0] + w * 2048;
#pragma unroll
  for (int tn = 0; tn < 2; ++tn) {
    const float* xrow = query + (b * 1024 + t0 + tn * 16 + c) * 1024 + h * 64;
    short8v af[2];
#pragma unroll
    for (int kh = 0; kh < 2; ++kh) {
      const float* xp = xrow + kh * 32 + g * 8;
      float4v x0 = *(const float4v*)xp;
      float4v x1 = *(const float4v*)(xp + 4);
      af[kh] = (short8v){ f2bf(x0.x), f2bf(x0.y), f2bf(x0.z), f2bf(x0.w),
                          f2bf(x1.x), f2bf(x1.y), f2bf(x1.z), f2bf(x1.w) };
    }
#pragma unroll
    for (int dn = 0; dn < 4; ++dn) {
      float4v acc = (float4v){0.f, 0.f, 0.f, 0.f};
#pragma unroll
      for (int kh = 0; kh < 2; ++kh) {
        const float* wp = Wq + (dn * 16 + c) * 64 + kh * 32 + g * 8;
        float4v w0 = *(const float4v*)wp;
        float4v w1 = *(const float4v*)(wp + 4);
        short8v bfr = (short8v){ f2bf(w0.x), f2bf(w0.y), f2bf(w0.z), f2bf(w0.w),
                                 f2bf(w1.x), f2bf(w1.y), f2bf(w1.z), f2bf(w1.w) };
        acc = MFMA_BF16(af[kh], bfr, acc);
      }
      const float bc = bq[dn * 16 + c];
#pragma unroll
      for (int r = 0; r < 4; ++r)
        qreg[(tn * 16 + 4 * g + r) * 64 + dn * 16 + c] =
            f2bf((acc[r] + bc) * QSCALE);
    }
  }

  asm volatile("" ::: "memory");   // order qreg write -> qreg read (same wave)

  short8v qf[2][2];                // same fragments r11 read from qs
#pragma unroll
  for (int tn = 0; tn < 2; ++tn)
#pragma unroll
    for (int kh = 0; kh < 2; ++kh)
      qf[tn][kh] = *(const short8v*)(qreg + (tn * 16 + c) * 64 + kh * 32 + g * 8);

  __syncthreads();                 // all waves done with kv -> reclaim for K/V

  // ---- r11 K/V staging + main loop (byte-identical) ----------------------
  const int kr = tid >> 3, kq = (tid & 7) ^ (kr & 7);
  const char* ksrc = (const char*)(kb + h * 65536) + kr * 128 + kq * 16;
  const int vd = tid >> 2, vq = (tid & 3) ^ ((vd >> 1) & 3);
  const char* vsrc = (const char*)(vt + h * 65536) + vd * 2048 + vq * 16;
  char* kdst = (char*)&kv[0][0] + tid * 16;
  char* vdst = (char*)&kv[0][0] + 4096 + tid * 16;

  int koff[2][2];
#pragma unroll
  for (int sm = 0; sm < 2; ++sm)
#pragma unroll
    for (int kh = 0; kh < 2; ++kh)
      koff[sm][kh] = (sm * 16 + c) * 128 + (((kh * 4 + g) ^ (c & 7)) * 16);
  int voff[4];
#pragma unroll
  for (int nt = 0; nt < 4; ++nt)
    voff[nt] = 4096 + (nt * 16 + c) * 64 + ((g ^ ((c >> 1) & 3)) * 16);

  float4v cacc[2][4];
#pragma unroll
  for (int tn = 0; tn < 2; ++tn)
#pragma unroll
    for (int nt = 0; nt < 4; ++nt)
      cacc[tn][nt] = (float4v){0.f, 0.f, 0.f, 0.f};
  float4v dacc[2];
  dacc[0] = (float4v){0.f, 0.f, 0.f, 0.f};
  dacc[1] = (float4v){0.f, 0.f, 0.f, 0.f};
  const short obf = (short)0x3F80;   // bf16 1.0
  const short8v ones = (short8v){obf, obf, obf, obf, obf, obf, obf, obf};

  short8v sk = *(const short8v*)ksrc;
  short8v sv = *(const short8v*)vsrc;
  *(short8v*)kdst = sk;
  *(short8v*)vdst = sv;

  const char* kv0 = (const char*)&kv[0][0];
  for (int i = 0; i < 32; ++i) {
    __syncthreads();            // buf(i&1) ready; other buf free for writes
    if (i < 31) {               // issue next-tile loads early
      sk = *(const short8v*)(ksrc + (i + 1) * 4096);
      sv = *(const short8v*)(vsrc + (i + 1) * 64);
    }

    const char* kvb = kv0 + (i & 1) * 8192;
    short8v kf[2][2];
#pragma unroll
    for (int sm = 0; sm < 2; ++sm)
#pragma unroll
      for (int kh = 0; kh < 2; ++kh)
        kf[sm][kh] = *(const short8v*)(kvb + koff[sm][kh]);
    short8v vf[4];
#pragma unroll
    for (int nt = 0; nt < 4; ++nt)
      vf[nt] = *(const short8v*)(kvb + voff[nt]);

    // scores^T -> exp2 -> cvt_pk pack into plds
#pragma unroll
    for (int sm = 0; sm < 2; ++sm)
#pragma unroll
      for (int tn = 0; tn < 2; ++tn) {
        float4v z = (float4v){0.f, 0.f, 0.f, 0.f};
        z = MFMA_BF16(kf[sm][0], qf[tn][0], z);
        z = MFMA_BF16(kf[sm][1], qf[tn][1], z);
        const float p0 = EXP2F(z[0]);
        const float p1 = EXP2F(z[1]);
        const float p2 = EXP2F(z[2]);
        const float p3 = EXP2F(z[3]);
        uint2 u;
        u.x = cvt_pk_bf16(p0, p1);   // s = 4g, 4g+1
        u.y = cvt_pk_bf16(p2, p3);   // s = 4g+2, 4g+3
        *(uint2*)&plds[w][tn][c][sm * 16 + 4 * g] = u;
      }

    asm volatile("" ::: "memory");   // order P write -> P read (same wave)

    short8v pa[2];
#pragma unroll
    for (int tn = 0; tn < 2; ++tn)
      pa[tn] = *(const short8v*)&plds[w][tn][c][g * 8];  // m=c(t), k=8g+j(s)

#pragma unroll
    for (int tn = 0; tn < 2; ++tn) {
#pragma unroll
      for (int nt = 0; nt < 4; ++nt)
        cacc[tn][nt] = MFMA_BF16(pa[tn], vf[nt], cacc[tn][nt]);
      dacc[tn] = MFMA_BF16(pa[tn], ones, dacc[tn]);   // rowsum(P), matrix pipe
    }

    asm volatile("" ::: "memory");

    if (i < 31) {   // write tile i+1 into the other buffer
      *(short8v*)(kdst + ((i + 1) & 1) * 8192) = sk;
      *(short8v*)(vdst + ((i + 1) & 1) * 8192) = sv;
    }
  }

  const int orow0 = b * 1024 + t0;
#pragma unroll
  for (int tn = 0; tn < 2; ++tn) {
    float inv[4];
#pragma unroll
    for (int r = 0; r < 4; ++r) inv[r] = 1.0f / dacc[tn][r];
#pragma unroll
    for (int nt = 0; nt < 4; ++nt)
#pragma unroll
      for (int r = 0; r < 4; ++r) {
        const int row = orow0 + tn * 16 + 4 * g + r;
        ctx[row * 1024 + h * 64 + nt * 16 + c] = f2bf(cacc[tn][nt][r] * inv[r]);
      }
  }
}

// ---------------------------------------------------------------------------
// Kernel 3: out = ctx(bf16) @ Wout^T + bout. r10/r11-exact (~8us measured):
// 512 blocks (32m x 16n, 128x64 tile) x 4 waves as 2m x 2n (64x32/wave).
// A+B LDS-staged dbuf; LDS content [r][ch] = X[r][ch ^ ((r>>1)&3)].
// ---------------------------------------------------------------------------
__global__ __launch_bounds__(256, 2) void out_proj(
    const short* __restrict__ ctx, const short* __restrict__ wb,
    const float* __restrict__ bout, float* __restrict__ out) {
  __shared__ __align__(16) short ab[2][6144];   // per buf: A 8KB | B 4KB
  const int tid = threadIdx.x;
  const int w = tid >> 6;
  const int lane = tid & 63;
  const int g = lane >> 4, c = lane & 15;
  const int wm = w >> 1, wn = w & 1;
  const int mblk = (blockIdx.x & 31) * 128;
  const int n0 = (blockIdx.x >> 5) * 64;

  // staging (256 threads): A rows srow & srow+64 (same chunk XOR), B rows srow.
  const int srow = tid >> 2;                   // 0..63
  const int sq = (tid & 3) ^ ((srow >> 1) & 3);
  const char* asrc0 = (const char*)ctx + (mblk + srow) * 2048 + sq * 16;
  const char* asrc1 = asrc0 + 64 * 2048;
  const char* bsrc  = (const char*)wb + (n0 + srow) * 2048 + sq * 16;
  char* adst0 = (char*)&ab[0][0] + tid * 16;
  char* adst1 = (char*)&ab[0][0] + 4096 + tid * 16;
  char* bdst  = (char*)&ab[0][0] + 8192 + tid * 16;

  const int sw = (g ^ ((c >> 1) & 3)) * 16;
  int aoff[4], boff[2];
#pragma unroll
  for (int mt = 0; mt < 4; ++mt)
    aoff[mt] = (wm * 64 + mt * 16 + c) * 64 + sw;
#pragma unroll
  for (int nt = 0; nt < 2; ++nt)
    boff[nt] = 8192 + (wn * 32 + nt * 16 + c) * 64 + sw;

  float4v acc[4][2];
#pragma unroll
  for (int mt = 0; mt < 4; ++mt)
#pragma unroll
    for (int nt = 0; nt < 2; ++nt)
      acc[mt][nt] = (float4v){0.f, 0.f, 0.f, 0.f};

  // prologue: k-tile 0 -> buf 0
  short8v sa0 = *(const short8v*)asrc0;
  short8v sa1 = *(const short8v*)asrc1;
  short8v sbv = *(const short8v*)bsrc;
  *(short8v*)adst0 = sa0;
  *(short8v*)adst1 = sa1;
  *(short8v*)bdst = sbv;

  const char* ab0 = (const char*)&ab[0][0];
  for (int i = 0; i < 32; ++i) {
    __syncthreads();
    if (i < 31) {
      sa0 = *(const short8v*)(asrc0 + (i + 1) * 64);
      sa1 = *(const short8v*)(asrc1 + (i + 1) * 64);
      sbv = *(const short8v*)(bsrc + (i + 1) * 64);
    }
    const char* abb = ab0 + (i & 1) * 12288;
    short8v a[4], bb[2];
#pragma unroll
    for (int mt = 0; mt < 4; ++mt)
      a[mt] = *(const short8v*)(abb + aoff[mt]);
#pragma unroll
    for (int nt = 0; nt < 2; ++nt)
      bb[nt] = *(const short8v*)(abb + boff[nt]);
#pragma unroll
    for (int mt = 0; mt < 4; ++mt)
#pragma unroll
      for (int nt = 0; nt < 2; ++nt)
        acc[mt][nt] = MFMA_BF16(a[mt], bb[nt], acc[mt][nt]);
    if (i < 31) {
      *(short8v*)(adst0 + ((i + 1) & 1) * 12288) = sa0;
      *(short8v*)(adst1 + ((i + 1) & 1) * 12288) = sa1;
      *(short8v*)(bdst + ((i + 1) & 1) * 12288) = sbv;
    }
  }

  float bs[2];
#pragma unroll
  for (int nt = 0; nt < 2; ++nt) bs[nt] = bout[n0 + wn * 32 + nt * 16 + c];

  const int m0 = mblk + wm * 64;
#pragma unroll
  for (int mt = 0; mt < 4; ++mt)
#pragma unroll
    for (int nt = 0; nt < 2; ++nt)
#pragma unroll
      for (int r = 0; r < 4; ++r)
        out[(m0 + mt * 16 + 4 * g + r) * 1024 + n0 + wn * 32 + nt * 16 + c] =
            acc[mt][nt][r] + bs[nt];
}

// ---------------------------------------------------------------------------
extern "C" void kernel_launch(void* const* d_in, const int* in_sizes, int n_in,
                              void* d_out, int out_size, void* d_ws, size_t ws_size,
                              hipStream_t stream) {
  const float* query = (const float*)d_in[0];
  const float* para  = (const float*)d_in[1];
  const float* Wq = (const float*)d_in[2];
  const float* bq = (const float*)d_in[3];
  const float* Wk = (const float*)d_in[4];
  const float* bk = (const float*)d_in[5];
  const float* Wv = (const float*)d_in[6];
  const float* bv = (const float*)d_in[7];
  const float* Wout = (const float*)d_in[8];
  const float* bout = (const float*)d_in[9];
  float* out = (float*)d_out;

  char* ws = (char*)d_ws;
  short* kb  = (short*)(ws + (8u  << 20));        // 2 MB
  short* vt  = (short*)(ws + (10u << 20));        // 2 MB
  short* ctx = (short*)(ws + (12u << 20));        // 8 MB
  short* wb  = (short*)(ws + (20u << 20));        // 2 MB

  proj_qkv<<<dim3(640), dim3(256), 0, stream>>>(para, Wk, bk, Wv, bv, Wout,
                                                kb, vt, wb);
  attn_fwd<<<dim3(512), dim3(256), 0, stream>>>(query, Wq, bq, kb, vt, ctx);
  out_proj<<<dim3(512), dim3(256), 0, stream>>>(ctx, wb, bout, out);
}